// Round 1
// baseline (1008.257 us; speedup 1.0000x reference)
//
#include <hip/hip_runtime.h>
#include <hip/hip_bf16.h>
#include <cstdint>
#include <math.h>

using u16 = unsigned short;
typedef __attribute__((ext_vector_type(8))) short bf16x8;
typedef __attribute__((ext_vector_type(4))) float f32x4;

#define BM 128
#define BN 128
#define BK 32

// round-to-nearest-even f32 -> bf16 (values are finite; no NaN path needed)
static __device__ __forceinline__ u16 f2bf(float f) {
    union { float f; unsigned int u; } v; v.f = f;
    return (u16)((v.u + 0x7FFFu + ((v.u >> 16) & 1u)) >> 16);
}

typedef const __attribute__((address_space(1))) unsigned int* gptr_t;
typedef __attribute__((address_space(3))) unsigned int* lptr_t;

static __device__ __forceinline__ void load_lds16(const void* g, void* l) {
    __builtin_amdgcn_global_load_lds((gptr_t)g, (lptr_t)l, 16, 0, 0);
}

// ---------------------------------------------------------------------------
// Kernel 1: transpose + fp32->bf16 cast of the 34 weight matrices.
// Wt slot layout: [0..15] W1_e members, [16] W1_s, [17..32] W2_e, [33] W2_s.
// Each slot is 1024x1024 bf16 stored TRANSPOSED: Wt[n][k] (n = output dim).
// ---------------------------------------------------------------------------
__global__ __launch_bounds__(256)
void wconv(const float* __restrict__ W1e, const float* __restrict__ W1s,
           const float* __restrict__ W2e, const float* __restrict__ W2s,
           u16* __restrict__ Wt)
{
    const int mat = blockIdx.z;
    const float* src;
    if (mat < 17) src = (mat < 16) ? (W1e + (size_t)mat * 1048576) : W1s;
    else {
        const int m2 = mat - 17;
        src = (m2 < 16) ? (W2e + (size_t)m2 * 1048576) : W2s;
    }
    u16* dst = Wt + (size_t)mat * 1048576;

    __shared__ float tile[32][33];
    const int tx = threadIdx.x & 31, ty = threadIdx.x >> 5;  // 32 x 8
    const int c0 = blockIdx.x * 32, r0 = blockIdx.y * 32;

#pragma unroll
    for (int j = 0; j < 32; j += 8)
        tile[ty + j][tx] = src[(size_t)(r0 + ty + j) * 1024 + c0 + tx];
    __syncthreads();
#pragma unroll
    for (int j = 0; j < 32; j += 8)
        dst[(size_t)(c0 + ty + j) * 1024 + r0 + tx] = f2bf(tile[tx][ty + j]);
}

// ---------------------------------------------------------------------------
// Kernel 2: LayerNorm, one wave per row, output bf16 in p-major grouped
// layout Y[p][b][d] so each GEMM slice p sees a dense 2048x1024 A matrix.
// ---------------------------------------------------------------------------
__global__ __launch_bounds__(256)
void ln_kernel(const float* __restrict__ x,
               const float* __restrict__ g_e, const float* __restrict__ b_e,
               const float* __restrict__ g_s, const float* __restrict__ b_s,
               u16* __restrict__ Yg)
{
    const int row  = blockIdx.x * 4 + (threadIdx.x >> 6);   // 0..65535
    const int lane = threadIdx.x & 63;
    const int b = row >> 5, p = row & 31;

    const float4* x4 = (const float4*)(x + (size_t)row * 1024) + lane * 4;
    float4 v[4];
    float sum = 0.f, ssq = 0.f;
#pragma unroll
    for (int i = 0; i < 4; i++) {
        v[i] = x4[i];
        sum += v[i].x + v[i].y + v[i].z + v[i].w;
        ssq += v[i].x * v[i].x + v[i].y * v[i].y + v[i].z * v[i].z + v[i].w * v[i].w;
    }
#pragma unroll
    for (int off = 32; off > 0; off >>= 1) {
        sum += __shfl_xor(sum, off);
        ssq += __shfl_xor(ssq, off);
    }
    const float mean = sum * (1.0f / 1024.0f);
    const float var  = ssq * (1.0f / 1024.0f) - mean * mean;   // biased, like jnp.var
    const float rstd = rsqrtf(var + 1e-5f);

    const float4* g4 = (const float4*)((p < 16) ? (g_e + p * 1024) : g_s) + lane * 4;
    const float4* b4 = (const float4*)((p < 16) ? (b_e + p * 1024) : b_s) + lane * 4;

    __attribute__((aligned(16))) u16 o[16];
#pragma unroll
    for (int i = 0; i < 4; i++) {
        const float4 g = g4[i], bb = b4[i];
        o[i * 4 + 0] = f2bf((v[i].x - mean) * rstd * g.x + bb.x);
        o[i * 4 + 1] = f2bf((v[i].y - mean) * rstd * g.y + bb.y);
        o[i * 4 + 2] = f2bf((v[i].z - mean) * rstd * g.z + bb.z);
        o[i * 4 + 3] = f2bf((v[i].w - mean) * rstd * g.w + bb.w);
    }
    u16* dst = Yg + ((size_t)p * 2048 + b) * 1024 + lane * 16;
    ((uint4*)dst)[0] = ((const uint4*)o)[0];
    ((uint4*)dst)[1] = ((const uint4*)o)[1];
}

// ---------------------------------------------------------------------------
// Kernels 3/4: batched bf16 GEMM, m97 recipe. A: [p][2048][1024] bf16 dense.
// B: Wt transposed layout [n][k]. 128x128 block tile, BK=32, 4 waves (2x2),
// each wave 64x64 via 4x4 mfma_f32_16x16x32_bf16. global_load_lds width=16.
// STAGE 1: +bias, exact gelu, bf16 out (grouped). STAGE 2: +bias, fp32 out
// to d_out at interleaved (b,p,k) positions.
// ---------------------------------------------------------------------------
template <int STAGE>
__global__ __launch_bounds__(256, 2)
void gemm_ffn(const u16* __restrict__ Abase, const u16* __restrict__ Wt,
              const float* __restrict__ bias_e, const float* __restrict__ bias_s,
              u16* __restrict__ Hout, float* __restrict__ Fout)
{
    const int p = blockIdx.z;
    const u16* Ap = Abase + (size_t)p * (2048u * 1024u);
    const u16* Bp = Wt + (size_t)((p < 16) ? p : 16) * (1024u * 1024u);
    const float* bias = (p < 16) ? (bias_e + p * 1024) : bias_s;

    const int m0 = blockIdx.y * BM;
    const int n0 = blockIdx.x * BN;

    __shared__ u16 Als[BM * BK];  // [m][k] row-major, 8 KB, unpadded (global_load_lds)
    __shared__ u16 Bls[BN * BK];  // [n][k] row-major, 8 KB

    const int t = threadIdx.x;
    const int w = t >> 6, l = t & 63;
    const int wm = (w >> 1) * 64, wn = (w & 1) * 64;
    const int lr = l & 15, kq = l >> 4;
    const int srow = t >> 2;          // staging row 0..63 per round
    const int sch  = (t & 3) * 8;     // staging k-chunk (ushort offset)

    f32x4 acc[4][4];
#pragma unroll
    for (int i = 0; i < 4; i++)
#pragma unroll
        for (int j = 0; j < 4; j++)
            acc[i][j] = (f32x4){0.f, 0.f, 0.f, 0.f};

    for (int k0 = 0; k0 < 1024; k0 += BK) {
#pragma unroll
        for (int r = 0; r < 2; r++) {
            const u16* ga = Ap + (size_t)(m0 + r * 64 + srow) * 1024 + (k0 + sch);
            const u16* gb = Bp + (size_t)(n0 + r * 64 + srow) * 1024 + (k0 + sch);
            load_lds16(ga, Als + (r * 256 + t) * 8);
            load_lds16(gb, Bls + (r * 256 + t) * 8);
        }
        __syncthreads();

        bf16x8 af[4], bfv[4];
#pragma unroll
        for (int i = 0; i < 4; i++)
            af[i] = *(const bf16x8*)(Als + (wm + i * 16 + lr) * BK + kq * 8);
#pragma unroll
        for (int j = 0; j < 4; j++)
            bfv[j] = *(const bf16x8*)(Bls + (wn + j * 16 + lr) * BK + kq * 8);
#pragma unroll
        for (int i = 0; i < 4; i++)
#pragma unroll
            for (int j = 0; j < 4; j++)
                acc[i][j] = __builtin_amdgcn_mfma_f32_16x16x32_bf16(af[i], bfv[j], acc[i][j], 0, 0, 0);
        __syncthreads();
    }

    float bv[4];
#pragma unroll
    for (int j = 0; j < 4; j++) bv[j] = bias[n0 + wn + j * 16 + lr];

#pragma unroll
    for (int i = 0; i < 4; i++) {
#pragma unroll
        for (int r = 0; r < 4; r++) {
            const int row = m0 + wm + i * 16 + kq * 4 + r;  // b index
#pragma unroll
            for (int j = 0; j < 4; j++) {
                const int col = n0 + wn + j * 16 + lr;
                float v2 = acc[i][j][r] + bv[j];
                if (STAGE == 1) {
                    v2 = 0.5f * v2 * (1.0f + erff(v2 * 0.70710678118654752f));  // exact gelu
                    Hout[(size_t)p * (2048u * 1024u) + (size_t)row * 1024 + col] = f2bf(v2);
                } else {
                    Fout[((size_t)row * 32 + p) * 1024 + col] = v2;
                }
            }
        }
    }
}

// ---------------------------------------------------------------------------
extern "C" void kernel_launch(void* const* d_in, const int* in_sizes, int n_in,
                              void* d_out, int out_size, void* d_ws, size_t ws_size,
                              hipStream_t stream)
{
    const float* x    = (const float*)d_in[0];
    const float* g_e  = (const float*)d_in[1];
    const float* b_e  = (const float*)d_in[2];
    const float* W1_e = (const float*)d_in[3];
    const float* b1_e = (const float*)d_in[4];
    const float* W2_e = (const float*)d_in[5];
    const float* b2_e = (const float*)d_in[6];
    const float* g_s  = (const float*)d_in[7];
    const float* b_s  = (const float*)d_in[8];
    const float* W1_s = (const float*)d_in[9];
    const float* b1_s = (const float*)d_in[10];
    const float* W2_s = (const float*)d_in[11];
    const float* b2_s = (const float*)d_in[12];
    float* out = (float*)d_out;

    // ws layout: Wt (34 * 1M bf16 = 68 MB) | Y (32*2048*1024 bf16 = 134 MB)
    //            | H (134 MB)  -> total ~340 MB
    u16* Wt = (u16*)d_ws;
    u16* Yg = Wt + (size_t)34 * 1024 * 1024;
    u16* Hg = Yg + (size_t)32 * 2048 * 1024;

    wconv<<<dim3(32, 32, 34), 256, 0, stream>>>(W1_e, W1_s, W2_e, W2_s, Wt);
    ln_kernel<<<16384, 256, 0, stream>>>(x, g_e, b_e, g_s, b_s, Yg);
    gemm_ffn<1><<<dim3(8, 16, 32), 256, 0, stream>>>(Yg, Wt, b1_e, b1_s, Hg, nullptr);
    gemm_ffn<2><<<dim3(8, 16, 32), 256, 0, stream>>>(Hg, Wt + (size_t)17 * 1024 * 1024,
                                                     b2_e, b2_s, nullptr, out);
}